// Round 15
// baseline (153.595 us; speedup 1.0000x reference)
//
#include <hip/hip_runtime.h>
#include <hip/hip_bf16.h>
#include <math.h>

#define LN2_F 0.69314718055994531f
#define INV_LN2_F 1.44269504088896341f
#define REGION_HALFS 2048   // one 16-row m-tile act region, K<=128, subtiled for tr-read (4 KB)
#define SLOT_SH 2048        // ring slot = 4 KB = 4 fragments x 1 KB

typedef _Float16 half8 __attribute__((ext_vector_type(8)));  // MFMA A/B frag (4 VGPRs)
typedef _Float16 h4_t __attribute__((ext_vector_type(4)));   // b64 / tr-read payload
typedef __fp16 pk2_t __attribute__((ext_vector_type(2)));    // cvt_pkrtz native type
typedef __attribute__((ext_vector_type(4))) float f32x4;     // MFMA C/D frag
typedef __attribute__((ext_vector_type(8))) short short8;

#define MFMA16(a, b, c) __builtin_amdgcn_mfma_f32_16x16x32_f16((a), (b), (c), 0, 0, 0)

// ---------------- weight prep: fp32 W -> f16 in B-fragment order ----------------
// B frag: lane l holds B[k = s*32 + (l>>4)*8 + j][n = ct*16 + (l&15)], j=0..7.
// ws layout (shorts): frag f = s*NT + ct at [f*512 + lane*8 + j] — lane-contiguous 1KB
// per fragment (exactly the global_load_lds source pattern). Layer bases (shorts):
// L0=0 (64x128,NT8), L1=8192 (128x128,NT8), L2=24576 (128x64,NT4), L3=32768 (64x32,NT2).
__global__ void prep_weights(const float* __restrict__ W0, const float* __restrict__ W1,
                             const float* __restrict__ W2, const float* __restrict__ W3,
                             short* __restrict__ ws) {
    int e = blockIdx.x * 256 + threadIdx.x;     // unit id, 4352 total
    const float* W; int N, NT, base, ul;
    if (e < 1024)      { W = W0; N = 128; NT = 8; base = 0;     ul = e; }
    else if (e < 3072) { W = W1; N = 128; NT = 8; base = 8192;  ul = e - 1024; }
    else if (e < 4096) { W = W2; N = 64;  NT = 4; base = 24576; ul = e - 3072; }
    else if (e < 4352) { W = W3; N = 32;  NT = 2; base = 32768; ul = e - 4096; }
    else return;
    const int cp = ul >> 6, lane = ul & 63;
    const int s = cp / NT, ct = cp % NT;
    const int k0 = s * 32 + (lane >> 4) * 8;
    const int n = ct * 16 + (lane & 15);
    union { half8 h; short8 s; } v;
#pragma unroll
    for (int j = 0; j < 8; ++j) v.h[j] = (_Float16)W[(size_t)(k0 + j) * N + n];
    *(short8*)(ws + base + cp * 512 + lane * 8) = v.s;
}

// ---------------- activation LDS tile (per 16-row m-tile) — VERIFIED r3..r14 ----------------
__device__ __forceinline__ void lds_fence() {
    asm volatile("s_waitcnt lgkmcnt(0)" ::: "memory");
}

__device__ __forceinline__ half8 tr_read_ks(const _Float16* region, unsigned lane_off, int s) {
    h4_t lo, hi;
    asm volatile("ds_read_b64_tr_b16 %0, %2\n\t"
                 "ds_read_b64_tr_b16 %1, %2 offset:128"
                 : "=&v"(lo), "=&v"(hi)
                 : "v"((unsigned)(uintptr_t)region + lane_off + (unsigned)(s * 1024))
                 : "memory");
    return __builtin_shufflevector(lo, hi, 0, 1, 2, 3, 4, 5, 6, 7);
}

__device__ __forceinline__ void store_tile(_Float16* __restrict__ region, int ct_global,
                                           int m, int q, f32x4 v) {
    const int base = ct_global * 256 + (m >> 2) * 64 + (m & 3) * 16 + q * 4;
    pk2_t p0 = __builtin_amdgcn_cvt_pkrtz(v[0], v[1]);
    pk2_t p1 = __builtin_amdgcn_cvt_pkrtz(v[2], v[3]);
    h4_t h = {(_Float16)p0[0], (_Float16)p0[1], (_Float16)p1[0], (_Float16)p1[1]};
    h = __builtin_elementwise_max(h, (h4_t)(_Float16)0.0f);   // relu: 2x v_pk_max_f16
    *(h4_t*)(region + base) = h;       // ds_write_b64
}

// ---------------- shared-ring staging: wave0 stages, all 4 waves consume ----------------
// gll: lane i's 16B (g + lane*16) -> lds + lane*16; ZERO VGPR cost (validated r10).
__device__ __forceinline__ void gll_frag(const short* g, short* l) {
    __builtin_amdgcn_global_load_lds(
        (const __attribute__((address_space(1))) void*)g,
        (__attribute__((address_space(3))) void*)l, 16, 0, 0);
}

template <int N>
__device__ __forceinline__ void wait_vmcnt() {
    asm volatile("s_waitcnt vmcnt(%0)" :: "n"(N) : "memory");
}

// one slice = 4 consecutive 1KB fragments from ws
__device__ __forceinline__ void stage4(const short* wl, int fb, short* slot, int lane8) {
#pragma unroll
    for (int c = 0; c < 4; ++c)
        gll_frag(wl + (size_t)(fb + c) * 512 + lane8, slot + c * 512);
}

// 17-slice pipeline, 3-slot ring, lookahead 2. Invariant: at the top of body k,
// slice k is LDS-resident (wave0 vmcnt'ed before the preceding barrier) and all
// waves have finished consuming slice k-1 (so staging slot (k+2)%3 == (k-1)%3 is safe).
// Raw s_barrier (+sched_barrier fences) — __syncthreads would emit vmcnt(0) and
// drain the lookahead (the m97 stall). Counted vmcnt(4) never reaches 0 mid-loop.
#define PIPE_STAGE(k)                                                              \
    do { if (wave == 0 && (k) + 2 <= 16)                                           \
        stage4(sp[(k) + 2], sfb[(k) + 2], ring + (((k) + 2) % 3) * SLOT_SH, lane8);\
    } while (0)

#define PIPE_END(k)                                                                \
    do {                                                                           \
        if (wave == 0) {                                                           \
            if ((k) + 2 <= 16) wait_vmcnt<4>();   /* slice k+1 landed */           \
            else wait_vmcnt<0>();                 /* final slice landed */         \
        }                                                                          \
        __builtin_amdgcn_sched_barrier(0);                                         \
        __builtin_amdgcn_s_barrier();                                              \
        __builtin_amdgcn_sched_barrier(0);                                         \
    } while (0)

#define ACC_INIT(bb, o)                                                            \
    do { _Pragma("unroll") for (int c = 0; c < 4; ++c) {                           \
        const float b_ = (bb)[(o) + c];                                            \
        acc[0][c] = f32x4{b_, b_, b_, b_};                                         \
        acc[1][c] = f32x4{b_, b_, b_, b_};                                         \
    } } while (0)

#define CONSUME(k, sidx)                                                           \
    do { const short* slot_ = ring + ((k) % 3) * SLOT_SH;                          \
        _Pragma("unroll") for (int c = 0; c < 4; ++c) {                            \
            half8 b_ = *(const half8*)(slot_ + c * 512 + lane8);                   \
            acc[0][c] = MFMA16(af[0][sidx], b_, acc[0][c]);                        \
            acc[1][c] = MFMA16(af[1][sidx], b_, acc[1][c]);                        \
        } } while (0)

#define STORE_HALF(ct0)                                                            \
    do { _Pragma("unroll") for (int mt = 0; mt < 2; ++mt)                          \
        _Pragma("unroll") for (int cc = 0; cc < 4; ++cc)                           \
            store_tile(lw + mt * REGION_HALFS, (ct0) + cc, m, q, acc[mt][cc]);     \
    } while (0)

#define TRANS(KS)                                                                  \
    do { lds_fence();                                                              \
        _Pragma("unroll") for (int mt = 0; mt < 2; ++mt)                           \
            _Pragma("unroll") for (int s_ = 0; s_ < (KS); ++s_)                    \
                af[mt][s_] = tr_read_ks(lw + mt * REGION_HALFS, lane_rd, s_);      \
        lds_fence();                                                               \
        __builtin_amdgcn_sched_barrier(0);                                         \
    } while (0)

__global__ __launch_bounds__(256, 4) void mlp_phi_mfma(
    const float* __restrict__ u,
    const float* __restrict__ b0, const float* __restrict__ b1,
    const float* __restrict__ b2, const float* __restrict__ b3,
    const short* __restrict__ ws,
    const float* __restrict__ var1, const float* __restrict__ var2,
    const float* __restrict__ var3, const float* __restrict__ var4,
    const float* __restrict__ var5, const float* __restrict__ var6,
    float* __restrict__ out) {
    // 4 waves/block, each wave owns 32 rows. LDS: act 32 KB + shared B-ring 12 KB
    // = 44 KB -> 3 blocks/CU (12 waves). B frags staged ONCE per block by wave0
    // (L2 weight traffic /4), consumed by all 4 waves from LDS.
    __shared__ __align__(16) _Float16 act[4 * 2 * REGION_HALFS];   // 32 KB
    __shared__ __align__(16) short ring[3 * SLOT_SH];              // 12 KB

    const int t = threadIdx.x, lane = t & 63, wave = t >> 6;
    const int m = lane & 15, q = lane >> 4;
    const int lane8 = lane * 8;                       // 16 B in shorts
    _Float16* lw = act + wave * 2 * REGION_HALFS;
    const unsigned lane_rd = (unsigned)(q * 256 + m * 8);
    const size_t row0 = (size_t)blockIdx.x * 128 + wave * 32;

    const short* wl0 = ws;
    const short* wl1 = ws + 8192;
    const short* wl2 = ws + 24576;
    const short* wl3 = ws + 32768;

    // slice table: (layer ptr, fragment base). L0: (s,h)=(0,0),(1,0),(0,1),(1,1);
    // L1 h0 s0..3; L1 h1 s0..3; L2 s0..3; L3 all-4-frags.
    const short* const sp[17] = {wl0, wl0, wl0, wl0,  wl1, wl1, wl1, wl1,
                                 wl1, wl1, wl1, wl1,  wl2, wl2, wl2, wl2,  wl3};
    const int sfb[17] = {0, 8, 4, 12,  0, 8, 16, 24,  4, 12, 20, 28,  0, 4, 8, 12,  0};

    // ---- hoisted biases (issued BEFORE any gll -> oldest in wave0's vmcnt queue) ----
    float bb0v[8], bb1v[8], bb2v[4], bb3v[2];
#pragma unroll
    for (int ct = 0; ct < 8; ++ct) bb0v[ct] = b0[ct * 16 + m];
#pragma unroll
    for (int ct = 0; ct < 8; ++ct) bb1v[ct] = b1[ct * 16 + m];
#pragma unroll
    for (int ct = 0; ct < 4; ++ct) bb2v[ct] = b2[ct * 16 + m];
#pragma unroll
    for (int ct = 0; ct < 2; ++ct) bb3v[ct] = b3[ct * 16 + m];

    half8 af[2][4];
    f32x4 acc[2][4];

    // ---- Layer 0 A-frags from global u + prologue staging of slices 0,1 ----
#pragma unroll
    for (int mt = 0; mt < 2; ++mt) {
        const float* up = u + (row0 + mt * 16 + m) * 64;
#pragma unroll
        for (int s = 0; s < 2; ++s) {
            float4 v0a = *(const float4*)(up + s * 32 + q * 8);
            float4 v1a = *(const float4*)(up + s * 32 + q * 8 + 4);
            pk2_t p0 = __builtin_amdgcn_cvt_pkrtz(v0a.x, v0a.y);
            pk2_t p1 = __builtin_amdgcn_cvt_pkrtz(v0a.z, v0a.w);
            pk2_t p2 = __builtin_amdgcn_cvt_pkrtz(v1a.x, v1a.y);
            pk2_t p3 = __builtin_amdgcn_cvt_pkrtz(v1a.z, v1a.w);
            af[mt][s] = half8{(_Float16)p0[0], (_Float16)p0[1], (_Float16)p1[0], (_Float16)p1[1],
                              (_Float16)p2[0], (_Float16)p2[1], (_Float16)p3[0], (_Float16)p3[1]};
        }
    }
    if (wave == 0) {
        stage4(sp[0], sfb[0], ring, lane8);
        stage4(sp[1], sfb[1], ring + SLOT_SH, lane8);
        wait_vmcnt<4>();   // slice 0 landed (drains older bias/u loads too — fine)
    }
    __builtin_amdgcn_sched_barrier(0);
    __builtin_amdgcn_s_barrier();
    __builtin_amdgcn_sched_barrier(0);

    // ---- Layer 0 (64 -> 128): slices 0-3 ----
    PIPE_STAGE(0); ACC_INIT(bb0v, 0); CONSUME(0, 0); PIPE_END(0);
    PIPE_STAGE(1); CONSUME(1, 1); STORE_HALF(0); PIPE_END(1);
    PIPE_STAGE(2); ACC_INIT(bb0v, 4); CONSUME(2, 0); PIPE_END(2);
    PIPE_STAGE(3); CONSUME(3, 1); STORE_HALF(4); TRANS(4); PIPE_END(3);

    // ---- Layer 1 (128 -> 128): slices 4-11 ----
    PIPE_STAGE(4); ACC_INIT(bb1v, 0); CONSUME(4, 0); PIPE_END(4);
    PIPE_STAGE(5); CONSUME(5, 1); PIPE_END(5);
    PIPE_STAGE(6); CONSUME(6, 2); PIPE_END(6);
    PIPE_STAGE(7); CONSUME(7, 3); STORE_HALF(0); PIPE_END(7);
    PIPE_STAGE(8); ACC_INIT(bb1v, 4); CONSUME(8, 0); PIPE_END(8);
    PIPE_STAGE(9); CONSUME(9, 1); PIPE_END(9);
    PIPE_STAGE(10); CONSUME(10, 2); PIPE_END(10);
    PIPE_STAGE(11); CONSUME(11, 3); STORE_HALF(4); TRANS(4); PIPE_END(11);

    // ---- Layer 2 (128 -> 64): slices 12-15 ----
    PIPE_STAGE(12); ACC_INIT(bb2v, 0); CONSUME(12, 0); PIPE_END(12);
    PIPE_STAGE(13); CONSUME(13, 1); PIPE_END(13);
    PIPE_STAGE(14); CONSUME(14, 2); PIPE_END(14);
    PIPE_STAGE(15); CONSUME(15, 3); STORE_HALF(0); TRANS(2); PIPE_END(15);

    // ---- Layer 3 (64 -> 32): slice 16 (slot 1), no barrier after ----
    // ue prefetch first: after the final vmcnt, safe on wave0; hides under L3+const loads.
    float ue[2][8];
#pragma unroll
    for (int mt = 0; mt < 2; ++mt)
#pragma unroll
        for (int ot = 0; ot < 2; ++ot)
#pragma unroll
            for (int r = 0; r < 4; ++r)
                ue[mt][ot * 4 + r] = u[(row0 + mt * 16 + q * 4 + r) * 64 + ot * 16 + m];
    {
        const short* slot_ = ring + (16 % 3) * SLOT_SH;
#pragma unroll
        for (int c = 0; c < 2; ++c) {
            const float b_ = bb3v[c];
            acc[0][c] = f32x4{b_, b_, b_, b_};
            acc[1][c] = f32x4{b_, b_, b_, b_};
        }
#pragma unroll
        for (int s = 0; s < 2; ++s)
#pragma unroll
            for (int c = 0; c < 2; ++c) {
                half8 b_ = *(const half8*)(slot_ + (s * 2 + c) * 512 + lane8);
                acc[0][c] = MFMA16(af[0][s], b_, acc[0][c]);
                acc[1][c] = MFMA16(af[1][s], b_, acc[1][c]);
            }
    }

    // ---- Epilogue: lane holds net[row=mt*16+q*4+r][col=ot*16+m] ----
    // log2-domain: L = log2(1-u), ln2 folded into per-d constants; exp(-x) == omu
    // exactly (x = -log(1-u)). u in [1e-4, 1-1e-4] => finite (nan_to_num no-op).
#pragma unroll
    for (int ot = 0; ot < 2; ++ot) {
        const int d = ot * 16 + m;
        const float v1 = var1[d], v6 = var6[d];
        const float v2p = var2[d] * INV_LN2_F;          // v2/ln2
        const float v4 = var4[d];
        const float v4p = v4 * INV_LN2_F;               // v4/ln2
        const float v5h = 0.5f * var5[d];
        const float v5hp = v5h * INV_LN2_F;             // v5h/ln2
        const float c3 = var3[d] - v4 - v5h;            // li coefficient
#pragma unroll
        for (int mt = 0; mt < 2; ++mt) {
#pragma unroll
            for (int r = 0; r < 4; ++r) {
                const size_t row = row0 + mt * 16 + q * 4 + r;
                const float net = acc[mt][ot][r];
                const float ud = ue[mt][ot * 4 + r];

                const float omu = 1.0f - ud;
                const float L = __log2f(omu);              // log2(1-u) < 0
                const float x = -L * LN2_F;                // -log(1-u), in (1e-4, 9.3)
                const float RL = __builtin_amdgcn_rcpf(L); // 1/log2(1-u)

                // E1 via Abramowitz-Stegun 5.1.53 (x<1) / 5.1.54 (x>=1)
                const float e1s = -__log2f(x) * LN2_F
                    + (-0.57721566f + x * (0.99999193f + x * (-0.24991055f
                    + x * (0.05519968f + x * (-0.00976004f + x * 0.00107857f)))));
                const float num = 0.2677737343f + x * (8.6347608925f + x * (18.0590169730f
                    + x * (8.5733287401f + x)));
                const float den = 3.9584969228f + x * (21.0996530827f + x * (25.6329561486f
                    + x * (9.5733223454f + x)));
                const float e1l = omu * num * __builtin_amdgcn_rcpf(x * den);  // exp(-x)=omu
                const float li = -((x < 1.0f) ? e1s : e1l); // _li(1-u)

                // phi = (v4*omu+v2)/lt + v5h*omu*(lt+1)/lt^2 + c3*li, log2 domain
                const float phi = fmaf(v4p, omu, v2p) * RL
                                + (v5hp * omu * (L + INV_LN2_F)) * RL * RL
                                + c3 * li;

                const float ud2 = ud * ud;
                const float ud4 = ud2 * ud2;
                const float p01 = ud4 * fmaf(-4.0f, ud, 5.0f);   // 5u^4 - 4u^5
                const float corr1 = p01 * (v1 + phi);
                const float d1 = ud - 1.0f;
                const float corr2 = v6 * ud * d1 * d1;           // u^3 - 2u^2 + u

                const float nt = fmaxf(net + corr1 + corr2, 0.0f);
                const float base = fmaf(-0.5f, ud2, 0.5f);       // (1-u^2)/2
                // base^(-nt) = exp2(-nt * log2(base)); v_exp_f32 is native exp2
                out[row * 32 + d] = __builtin_amdgcn_exp2f(-nt * __log2f(base));
            }
        }
    }
}

extern "C" void kernel_launch(void* const* d_in, const int* in_sizes, int n_in,
                              void* d_out, int out_size, void* d_ws, size_t ws_size,
                              hipStream_t stream) {
    const float* u    = (const float*)d_in[0];
    const float* W0   = (const float*)d_in[1];
    const float* b0   = (const float*)d_in[2];
    const float* W1   = (const float*)d_in[3];
    const float* b1   = (const float*)d_in[4];
    const float* W2   = (const float*)d_in[5];
    const float* b2   = (const float*)d_in[6];
    const float* W3   = (const float*)d_in[7];
    const float* b3   = (const float*)d_in[8];
    const float* var1 = (const float*)d_in[9];
    const float* var2 = (const float*)d_in[10];
    const float* var3 = (const float*)d_in[11];
    const float* var4 = (const float*)d_in[12];
    const float* var5 = (const float*)d_in[13];
    const float* var6 = (const float*)d_in[14];
    float* out = (float*)d_out;
    short* ws = (short*)d_ws;   // needs 69,632 B

    // Convert weights to f16 fragment layout (same work every launch).
    prep_weights<<<dim3(17), dim3(256), 0, stream>>>(W0, W1, W2, W3, ws);

    const int B = in_sizes[0] / 64;        // 262144 rows
    const int blocks = B / 128;            // 128 rows per block (32 per wave)
    mlp_phi_mfma<<<dim3(blocks), dim3(256), 0, stream>>>(
        u, b0, b1, b2, b3, ws,
        var1, var2, var3, var4, var5, var6, out);
}